// Round 2
// baseline (345.110 us; speedup 1.0000x reference)
//
#include <hip/hip_runtime.h>

typedef unsigned short u16;
typedef unsigned int   u32;
typedef __attribute__((ext_vector_type(8))) short bf16x8;
typedef __attribute__((ext_vector_type(4))) float f32x4;
typedef __attribute__((ext_vector_type(4))) u32   u32x4;

#define BB   2
#define NCH  32      // CI == CO == 32
#define DD   64
#define PD   66      // padded spatial dim (zero halo)
#define NTAP 27

__device__ __forceinline__ u16 f2bf(float f) {
  u32 u = __float_as_uint(f);
  u = (u + 0x7fffu + ((u >> 16) & 1u)) >> 16;   // RNE
  return (u16)u;
}

// ---- Kernel 0: pack w1/w2/w3 into bf16 B-fragment layout -------------------
// wb[og][tap][nf][lane][j] ; B-frag: col = lane&15 (o-o0), k = 8*(lane>>4)+j (ci)
__global__ void pack_w_kernel(const float* __restrict__ w1,
                              const float* __restrict__ w2,
                              const float* __restrict__ w3,
                              u16* __restrict__ wb) {
  int i = blockIdx.x * 256 + threadIdx.x;
  if (i >= NTAP * 3 * 2 * 64 * 8) return;
  int j    = i & 7;
  int lane = (i >> 3) & 63;
  int q    = i >> 9;           // og? no: q = ((og*27+tap)*3+nf)
  int nf   = q % 3;
  int tap  = (q / 3) % NTAP;
  int og   = q / (3 * NTAP);
  int o  = og * 16 + (lane & 15);
  int ci = (lane >> 4) * 8 + j;
  const float* ws = (nf == 0) ? w1 : (nf == 1) ? w2 : w3;
  wb[i] = f2bf(ws[((size_t)o * NTAP + tap) * NCH + ci]);
}

// ---- Kernel 1a: zero the halo of xl ---------------------------------------
__global__ void zero_halo_kernel(u16* __restrict__ xl) {
  int tid = blockIdx.x * 256 + threadIdx.x;
  if (tid >= BB * PD * PD * PD) return;
  int xp = tid % PD;
  int t  = tid / PD;
  int yp = t % PD;  t /= PD;
  int zp = t % PD;
  if (xp && yp && zp && xp < PD - 1 && yp < PD - 1 && zp < PD - 1) return;
  u32x4 z4 = {0u, 0u, 0u, 0u};
  u32x4* dst = (u32x4*)(xl + (size_t)tid * NCH);
#pragma unroll
  for (int i = 0; i < 4; i++) dst[i] = z4;
}

// ---- Kernel 1b: interior xl = log(x), channels-last bf16, via LDS transpose
// block = 256 thr handles one (b,z,y) row: 64 voxels x 32 channels.
__global__ __launch_bounds__(256) void build_xl_kernel(const float* __restrict__ x,
                                                       u16* __restrict__ xl) {
  __shared__ __align__(16) u16 lds[64][40];   // 5120 B, rows 80B (16B-aligned)
  int bi = blockIdx.x;                 // b*4096 + z*64 + y
  int y = bi & 63;
  int z = (bi >> 6) & 63;
  int b = bi >> 12;
  int tid = threadIdx.x;
  int xo = tid & 63, wv = tid >> 6;

  const float* xb = x + (size_t)b * NCH * DD * DD * DD
                      + ((size_t)z * DD + y) * DD + xo;
#pragma unroll
  for (int it = 0; it < 8; it++) {
    int c = it * 4 + wv;
    float v = xb[(size_t)c * (DD * DD * DD)];
    lds[xo][c] = f2bf(__logf(v));
  }
  __syncthreads();
  int vx = tid >> 2, ch = tid & 3;
  bf16x8 val = *(const bf16x8*)&lds[vx][ch * 8];
  u16* dst = xl + ((((size_t)b * PD + z + 1) * PD + y + 1) * PD + (vx + 1)) * NCH
                + ch * 8;
  *(bf16x8*)dst = val;
}

// ---- Kernel 2: 27-tap implicit GEMM + fused Volterra epilogue --------------
// block = 256 thr (4 waves). wave = 2 x-rows (128 voxels) x 48 ch (o-group w1/w2/w3).
// No LDS, no syncthreads; B-frags from global (L1/L2-hot packed weights).
// grid: og(2) * ytile(8) * z(64) * b(2) = 2048 blocks.
__global__ __launch_bounds__(256, 3) void conv_volterra_kernel(
    const u16* __restrict__ xl, const u16* __restrict__ wb,
    const float* __restrict__ x, float* __restrict__ out) {
  int bi = blockIdx.x;
  const int og = bi & 1;
  int t = bi >> 1;
  const int ytile = t & 7;  t >>= 3;
  const int z = t & 63;
  const int b = t >> 6;
  const int tid = threadIdx.x;
  const int wv = tid >> 6;
  const int lane = tid & 63;
  const int l15 = lane & 15;
  const int l4 = lane >> 4;
  const int y0 = ytile * 8 + wv * 2;
  const int o0 = og * 16;

  f32x4 acc[8][3];
#pragma unroll
  for (int mf = 0; mf < 8; mf++)
#pragma unroll
    for (int nf = 0; nf < 3; nf++)
      acc[mf][nf] = (f32x4){0.f, 0.f, 0.f, 0.f};

  // A fragment: row = lane&15 -> x-voxel, k = 8*(lane>>4)+j -> ci (channels-last)
  const u16* xlb = xl + (size_t)b * PD * PD * PD * NCH
                 + ((size_t)z * PD + y0) * PD * NCH + l15 * NCH + l4 * 8;
  const u16* wbase = wb + (size_t)og * (NTAP * 3 * 512) + lane * 8;

#pragma unroll
  for (int kd = 0; kd < 3; kd++)
#pragma unroll
    for (int kh = 0; kh < 3; kh++)
#pragma unroll
      for (int kw = 0; kw < 3; kw++) {
        const int tap = (kd * 3 + kh) * 3 + kw;
        const u16* p0 = xlb + ((kd * PD + kh) * PD + kw) * NCH;
        bf16x8 a[8];
#pragma unroll
        for (int mf = 0; mf < 4; mf++)
          a[mf] = *(const bf16x8*)(p0 + mf * 16 * NCH);
        const u16* p1 = p0 + PD * NCH;
#pragma unroll
        for (int mf = 0; mf < 4; mf++)
          a[4 + mf] = *(const bf16x8*)(p1 + mf * 16 * NCH);
        bf16x8 bwf[3];
#pragma unroll
        for (int nf = 0; nf < 3; nf++)
          bwf[nf] = *(const bf16x8*)(wbase + (tap * 3 + nf) * 512);
#pragma unroll
        for (int mf = 0; mf < 8; mf++)
#pragma unroll
          for (int nf = 0; nf < 3; nf++)
            acc[mf][nf] = __builtin_amdgcn_mfma_f32_16x16x32_bf16(
                a[mf], bwf[nf], acc[mf][nf], 0, 0, 0);
      }

  // ---- fused epilogue: out = x * exp(l1 + l2*l3), lane-local channels ----
  const int o = o0 + l15;
  const size_t base_bo = (size_t)(b * NCH + o) * (DD * DD * DD) + (size_t)z * DD * DD;
#pragma unroll
  for (int mf = 0; mf < 8; mf++) {
    int yrow = y0 + (mf >> 2);
    int xc = (mf & 3) * 16 + l4 * 4;
    size_t idx = base_bo + (size_t)yrow * DD + xc;
    f32x4 xv = *(const f32x4*)(x + idx);
    f32x4 r;
#pragma unroll
    for (int j = 0; j < 4; j++)
      r[j] = xv[j] * __expf(acc[mf][0][j] + acc[mf][1][j] * acc[mf][2][j]);
    *(f32x4*)(out + idx) = r;
  }
}

extern "C" void kernel_launch(void* const* d_in, const int* in_sizes, int n_in,
                              void* d_out, int out_size, void* d_ws, size_t ws_size,
                              hipStream_t stream) {
  const float* x  = (const float*)d_in[0];
  const float* w1 = (const float*)d_in[1];
  const float* w2 = (const float*)d_in[2];
  const float* w3 = (const float*)d_in[3];
  float* out = (float*)d_out;
  u16* xl = (u16*)d_ws;                                  // 2*66^3*32 bf16 = 36.8 MB
  u16* wb = xl + (size_t)BB * PD * PD * PD * NCH;        // +166 KB packed weights

  pack_w_kernel<<<(NTAP * 3 * 2 * 64 * 8 + 255) / 256, 256, 0, stream>>>(w1, w2, w3, wb);
  const int npad = BB * PD * PD * PD;
  zero_halo_kernel<<<(npad + 255) / 256, 256, 0, stream>>>(xl);
  build_xl_kernel<<<BB * DD * DD, 256, 0, stream>>>(x, xl);
  conv_volterra_kernel<<<2048, 256, 0, stream>>>(xl, wb, x, out);
}

// Round 4
// 188.240 us; speedup vs baseline: 1.8334x; 1.8334x over previous
//
#include <hip/hip_runtime.h>

typedef unsigned short u16;
typedef unsigned int   u32;
typedef __attribute__((ext_vector_type(8)))  short bf16x8;
typedef __attribute__((ext_vector_type(4)))  float f32x4;
typedef __attribute__((ext_vector_type(4)))  u32   u32x4;

#define BB   2
#define NCH  32
#define DD   64
#define PD   66
#define NTAP 27
#define D3   (DD * DD * DD)

#define NROW 18                     // 3 z-planes * 6 y-rows staged per block
#define XCHK 68                     // x chunks per row (66 used, 2 pad unread)
#define RS   (XCHK * 8)             // row stride, u16
#define QS   (NROW * RS + 8)        // quarter stride, u16 (+1 chunk = bank rotation)

__device__ __forceinline__ u16 f2bf(float f) {
  u32 u = __float_as_uint(f);
  u = (u + 0x7fffu + ((u >> 16) & 1u)) >> 16;   // RNE
  return (u16)u;
}

__device__ __forceinline__ void glds16(const u16* g, u16* l) {
  __builtin_amdgcn_global_load_lds(
      (const __attribute__((address_space(1))) u32*)(const void*)g,
      (__attribute__((address_space(3))) u32*)(void*)l, 16, 0, 0);
}

// ---- Kernel 0: pack w1/w2/w3 into 16x16x32 B-fragment layout ---------------
// wb[((tap*3+c)*2+nh)*512 + lane*8 + j] = w_c[o=nh*16+(lane&15)][tap][ci=8*(lane>>4)+j]
__global__ void pack_w_kernel(const float* __restrict__ w1,
                              const float* __restrict__ w2,
                              const float* __restrict__ w3,
                              u16* __restrict__ wb) {
  int i = blockIdx.x * 256 + threadIdx.x;
  if (i >= NTAP * 3 * 2 * 512) return;
  int j    = i & 7;
  int lane = (i >> 3) & 63;
  int nh   = (i >> 9) & 1;
  int q    = i >> 10;            // tap*3 + c
  int c    = q % 3;
  int tap  = q / 3;
  int o  = nh * 16 + (lane & 15);
  int ci = (lane >> 4) * 8 + j;
  const float* ws = (c == 0) ? w1 : (c == 1) ? w2 : w3;
  wb[i] = f2bf(ws[(size_t)o * (NTAP * NCH) + tap * NCH + ci]);
}

// ---- Kernel 1a: zero the halo of xl ---------------------------------------
__global__ void zero_halo_kernel(u16* __restrict__ xl) {
  int tid = blockIdx.x * 256 + threadIdx.x;
  if (tid >= BB * PD * PD * PD) return;
  int xp = tid % PD;
  int t  = tid / PD;
  int yp = t % PD;  t /= PD;
  int zp = t % PD;
  if (xp && yp && zp && xp < PD - 1 && yp < PD - 1 && zp < PD - 1) return;
  u32x4 z4 = {0u, 0u, 0u, 0u};
  u32x4* dst = (u32x4*)(xl + (size_t)tid * NCH);
#pragma unroll
  for (int i = 0; i < 4; i++) dst[i] = z4;
}

// ---- Kernel 1b: interior xl = log(x) -> channels-last bf16 -----------------
__global__ __launch_bounds__(256) void build_xl_kernel(const float* __restrict__ x,
                                                       u16* __restrict__ xl) {
  __shared__ __align__(16) u16 lds[256][40];
  int bi = blockIdx.x;            // b*1024 + z*16 + yt
  int yt = bi & 15;
  int z  = (bi >> 4) & 63;
  int b  = bi >> 10;
  int t  = threadIdx.x;
  int x4 = t & 15, yy = (t >> 4) & 3, c0 = t >> 6;
  int y0 = yt * 4;

  const float* src = x + (size_t)b * NCH * D3 + ((size_t)z * DD + (y0 + yy)) * DD + x4 * 4;
  int v0 = yy * 64 + x4 * 4;
#pragma unroll
  for (int p = 0; p < 8; p++) {
    int c = c0 + 4 * p;
    f32x4 f = *(const f32x4*)(src + (size_t)c * D3);
#pragma unroll
    for (int k = 0; k < 4; k++) lds[v0 + k][c] = f2bf(__logf(f[k]));
  }
  __syncthreads();

  int vy = t >> 6, vx = t & 63;
  u16* dst = xl + ((((size_t)b * PD + (z + 1)) * PD + (y0 + vy + 1)) * PD + (vx + 1)) * NCH;
#pragma unroll
  for (int q = 0; q < 4; q++)
    *(bf16x8*)(dst + q * 8) = *(const bf16x8*)&lds[t][q * 8];
}

// ---- Kernel 2: LDS-staged 27-tap implicit GEMM (16x16x32) + fused epilogue -
// block = 256 thr / 4 waves = (y-pair p, o-half nh); block tile = 4 y-rows,
// full x (64), all 32 o. LDS: [q 4][row 18][x 68][16B], quarter-padded.
__global__ __launch_bounds__(256, 2) void conv_volterra_kernel(
    const u16* __restrict__ xl, const u16* __restrict__ wb,
    const float* __restrict__ x, float* __restrict__ out) {
  __shared__ __align__(16) u16 tile[4 * QS];   // 78,400 B

  // XCD z-affinity: xcd = blk&7 owns z in [8*xcd, 8*xcd+8)
  int i = blockIdx.x;
  int xcd = i & 7, r = i >> 3;
  int z  = xcd * 8 + (r >> 5);
  int yt = (r >> 1) & 15;
  int b  = r & 1;
  int y0 = yt * 4;

  int tid = threadIdx.x, wv = tid >> 6, lane = tid & 63;
  int l15 = lane & 15, l4 = lane >> 4;
  int p = wv >> 1, nh = wv & 1;

  const u16* gbase = xl + (((size_t)b * PD + z) * PD + y0) * PD * NCH;

  // main staging: wave wv stages quarter q=wv, x in [0,64) — FULL-WAVE glds only
  {
    u16* ldsq = tile + wv * QS;
#pragma unroll
    for (int rr = 0; rr < NROW; ++rr) {
      const int zs = rr / 6, yr = rr % 6;              // compile-time
      glds16(gbase + ((size_t)(zs * PD + yr)) * PD * NCH + lane * NCH + wv * 8,
             ldsq + rr * RS);
    }
  }
  // tail: x = 64,65 of every (q,row): 144 chunks via plain load + ds_write
  if (tid < 144) {
    int q = tid & 3, u = tid >> 2;                     // u in [0,36)
    int rr = u >> 1, xt = 64 + (u & 1);
    int zs = rr / 6, yr = rr - zs * 6;
    const u16* g = gbase + ((size_t)(zs * PD + yr)) * PD * NCH + xt * NCH + q * 8;
    u32x4 v = *(const u32x4*)g;
    *(u32x4*)(tile + q * QS + rr * RS + xt * 8) = v;
  }
  __syncthreads();

  f32x4 acc[3][8];
#pragma unroll
  for (int c = 0; c < 3; c++)
#pragma unroll
    for (int m = 0; m < 8; m++)
      acc[c][m] = (f32x4){0.f, 0.f, 0.f, 0.f};

  // A frag: voxel row = lane&15 (+x base), k-quarter = lane>>4 (verified r1/r2)
  const u16* A0 = tile + (size_t)l4 * QS + (size_t)(2 * p) * RS + (size_t)l15 * 8;
  const u16* wB = wb + nh * 512 + lane * 8;

#pragma unroll
  for (int kd = 0; kd < 3; ++kd)
#pragma unroll
    for (int khy = 0; khy < 3; ++khy)
#pragma unroll
      for (int kw = 0; kw < 3; ++kw) {
        const int tap = (kd * 3 + khy) * 3 + kw;
        bf16x8 bwf[3];
#pragma unroll
        for (int c = 0; c < 3; c++)
          bwf[c] = *(const bf16x8*)(wB + (size_t)(tap * 3 + c) * 1024);
        bf16x8 a[8];
#pragma unroll
        for (int m = 0; m < 8; m++)
          a[m] = *(const bf16x8*)(A0 + (kd * 6 + (m >> 2) + khy) * RS
                                     + ((m & 3) * 16 + kw) * 8);
#pragma unroll
        for (int m = 0; m < 8; m++)
#pragma unroll
          for (int c = 0; c < 3; c++)
            acc[c][m] = __builtin_amdgcn_mfma_f32_16x16x32_bf16(
                a[m], bwf[c], acc[c][m], 0, 0, 0);
      }

  // ---- fused epilogue: out = x * exp(l1 + l2*l3) ---------------------------
  const int o = nh * 16 + l15;
  const int ybase = y0 + 2 * p;
  const size_t pb = (size_t)(b * NCH + o) * D3 + (size_t)z * DD * DD;
#pragma unroll
  for (int m = 0; m < 8; m++) {
    int y  = ybase + (m >> 2);
    int xc = (m & 3) * 16 + l4 * 4;
    size_t idx = pb + (size_t)y * DD + xc;
    f32x4 xv = *(const f32x4*)(x + idx);
    f32x4 rr;
#pragma unroll
    for (int j = 0; j < 4; j++)
      rr[j] = xv[j] * __expf(acc[0][m][j] + acc[1][m][j] * acc[2][m][j]);
    *(f32x4*)(out + idx) = rr;
  }
}

extern "C" void kernel_launch(void* const* d_in, const int* in_sizes, int n_in,
                              void* d_out, int out_size, void* d_ws, size_t ws_size,
                              hipStream_t stream) {
  const float* x  = (const float*)d_in[0];
  const float* w1 = (const float*)d_in[1];
  const float* w2 = (const float*)d_in[2];
  const float* w3 = (const float*)d_in[3];
  float* out = (float*)d_out;
  u16* xl = (u16*)d_ws;                                  // 2*66^3*32 bf16 = 36.8 MB
  u16* wb = xl + (size_t)BB * PD * PD * PD * NCH;        // +166 KB packed weights

  pack_w_kernel<<<(NTAP * 3 * 2 * 512 + 255) / 256, 256, 0, stream>>>(w1, w2, w3, wb);
  const int npad = BB * PD * PD * PD;
  zero_halo_kernel<<<(npad + 255) / 256, 256, 0, stream>>>(xl);
  build_xl_kernel<<<BB * DD * 16, 256, 0, stream>>>(x, xl);
  conv_volterra_kernel<<<2048, 256, 0, stream>>>(xl, wb, x, out);
}